// Round 1
// baseline (716.624 us; speedup 1.0000x reference)
//
#include <hip/hip_runtime.h>
#include <math.h>

#define NEGV -1000000000.0f
#define EPSV 1e-38f

constexpr int B = 16, T = 32, K = 512, N = 24, V = 32000, H = 128;
constexpr int N2 = N * N;     // 576
constexpr int N3 = N * N * N; // 13824

// ---------------------------------------------------------------- frontend
// One block per (b,t): LayerNorm(512) -> h=gelu(g@W1+b1) (128) -> out=h@W2+b2 (24)
// -> log_softmax over N -> Phi[b,n,t]
__global__ void __launch_bounds__(128) frontend_kernel(
    const float* __restrict__ g_seq, const float* __restrict__ ln_gamma,
    const float* __restrict__ ln_beta, const float* __restrict__ W1,
    const float* __restrict__ b1, const float* __restrict__ W2,
    const float* __restrict__ b2, float* __restrict__ Phi) {
  int bt = blockIdx.x;          // 0..511
  int b = bt >> 5, t = bt & 31;
  int tid = threadIdx.x;        // 0..127
  __shared__ __align__(16) float g[K];
  __shared__ float red[128];
  __shared__ float hbuf[H];
  __shared__ float obuf[N];
  __shared__ float stats[2];

  float4 v = ((const float4*)(g_seq + bt * K))[tid];
  ((float4*)g)[tid] = v;
  float s = v.x + v.y + v.z + v.w;
  float sq = v.x * v.x + v.y * v.y + v.z * v.z + v.w * v.w;

  red[tid] = s; __syncthreads();
  for (int off = 64; off > 0; off >>= 1) { if (tid < off) red[tid] += red[tid + off]; __syncthreads(); }
  if (tid == 0) stats[0] = red[0] / (float)K;
  __syncthreads();
  red[tid] = sq; __syncthreads();
  for (int off = 64; off > 0; off >>= 1) { if (tid < off) red[tid] += red[tid + off]; __syncthreads(); }
  if (tid == 0) {
    float mu = stats[0];
    float var = red[0] / (float)K - mu * mu;
    stats[1] = rsqrtf(var + 1e-5f);
  }
  __syncthreads();
  float mu = stats[0], rstd = stats[1];
  for (int c = tid; c < K; c += 128)
    g[c] = (g[c] - mu) * rstd * ln_gamma[c] + ln_beta[c];
  __syncthreads();

  // h[tid] = gelu(dot(g, W1[:,tid]) + b1[tid])
  float acc = b1[tid];
  for (int c = 0; c < K; c++) acc = fmaf(g[c], W1[c * H + tid], acc);
  float ge = 0.5f * acc * (1.0f + erff(acc * 0.70710678118654752f));
  hbuf[tid] = ge;
  __syncthreads();

  if (tid < N) {
    float o = b2[tid];
    for (int jj = 0; jj < H; jj++) o = fmaf(hbuf[jj], W2[jj * N + tid], o);
    obuf[tid] = o;
  }
  __syncthreads();
  if (tid == 0) {
    float m = obuf[0];
    for (int n = 1; n < N; n++) m = fmaxf(m, obuf[n]);
    float ssum = 0.f;
    for (int n = 0; n < N; n++) ssum += expf(obuf[n] - m);
    stats[0] = m + logf(ssum);
  }
  __syncthreads();
  if (tid < N) Phi[(b * N + tid) * T + t] = obuf[tid] - stats[0];
}

// ---------------------------------------------------------------- theta prep
// theta_log = Theta - logsumexp_z; tm = max(theta_log); et = exp(theta_log - tm)
// also etT[(y*N+z)*N+x] = et[x,y,z] for the outside pass.
__global__ void theta_prep(const float* __restrict__ Theta,
                           float* __restrict__ et, float* __restrict__ etT,
                           float* __restrict__ tmv) {
  int tid = threadIdx.x; // 0..575 (row = x*N+y)
  __shared__ float wmax[9];
  const float* row = Theta + tid * N;
  float vals[N];
  float m = row[0];
  for (int z = 1; z < N; z++) m = fmaxf(m, row[z]);
  float ssum = 0.f;
  for (int z = 0; z < N; z++) { vals[z] = row[z]; ssum += expf(row[z] - m); }
  float lse = m + logf(ssum);
  float rmax = m - lse;

  float wm = rmax;
  for (int off = 32; off > 0; off >>= 1) wm = fmaxf(wm, __shfl_down(wm, off));
  if ((tid & 63) == 0) wmax[tid >> 6] = wm;
  __syncthreads();
  if (tid == 0) {
    float tm = wmax[0];
    for (int w = 1; w < 9; w++) tm = fmaxf(tm, wmax[w]);
    wmax[0] = tm;
    tmv[0] = tm;
  }
  __syncthreads();
  float tm = wmax[0];
  int x = tid / N, y = tid - (tid / N) * N;
  for (int z = 0; z < N; z++) {
    float e = expf(vals[z] - lse - tm);
    et[tid * N + z] = e;
    etT[(y * N + z) * N + x] = e;
  }
}

// ---------------------------------------------------------------- init
__global__ void init_kernel(const float* __restrict__ Phi,
                            float* __restrict__ beta, float* __restrict__ alpha) {
  int idx = blockIdx.x * 256 + threadIdx.x;
  if (idx < B * N * T * T) {
    // alpha = NEG everywhere except [b,0,0,T-1] = 0
    alpha[idx] = ((idx % (N * T * T)) == (T - 1)) ? 0.f : NEGV;
  }
  if (idx < B * N * T) {
    int t = idx & 31, bn = idx >> 5;
    beta[bn * T * T + t * T + t] = Phi[idx];
  }
}

// ---------------------------------------------------------------- inside
// block (i,b): beta[b,x,i,j] = tm + M + log( sum_{y,z} et[x,y,z] * r[y,z] )
// r[y,z] = sum_s exp(left[y,s]+right[z,s]-M), M = max_s(ml_s+mr_s)
__global__ void __launch_bounds__(256) inside_level(
    const float* __restrict__ et, const float* __restrict__ tmv,
    float* __restrict__ beta, int l) {
  int i = blockIdx.x, b = blockIdx.y;
  int j = i + l - 1, S = l - 1, tid = threadIdx.x;
  __shared__ __align__(16) float Am[31 * N];
  __shared__ __align__(16) float Bm[31 * N];
  __shared__ float mr[31], msum[31];
  __shared__ __align__(16) float r[N2];
  __shared__ float partial[192];
  __shared__ float Msh;
  const float* bb = beta + b * N * T * T;

  for (int idx = tid; idx < S * N; idx += 256) {
    int s = idx / N, y = idx - s * N;
    Am[idx] = bb[y * T * T + i * T + (i + s)];
    Bm[idx] = bb[y * T * T + (i + s + 1) * T + j];
  }
  __syncthreads();
  if (tid < S) {
    float ml = Am[tid * N], mrr = Bm[tid * N];
    for (int y = 1; y < N; y++) {
      ml = fmaxf(ml, Am[tid * N + y]);
      mrr = fmaxf(mrr, Bm[tid * N + y]);
    }
    mr[tid] = mrr; msum[tid] = ml + mrr;
  }
  __syncthreads();
  if (tid == 0) {
    float M = msum[0];
    for (int s = 1; s < S; s++) M = fmaxf(M, msum[s]);
    Msh = M;
  }
  __syncthreads();
  float M = Msh;
  for (int idx = tid; idx < S * N; idx += 256) {
    int s = idx / N;
    Am[idx] = expf(Am[idx] + mr[s] - M);   // <= 1
    Bm[idx] = expf(Bm[idx] - mr[s]);       // <= 1
  }
  __syncthreads();
  for (int p = tid; p < N2; p += 256) {
    int y = p / N, z = p - (p / N) * N;
    float acc = 0.f;
    for (int s = 0; s < S; s++) acc = fmaf(Am[s * N + y], Bm[s * N + z], acc);
    r[p] = acc;
  }
  __syncthreads();
  if (tid < 192) {
    int x = tid >> 3, part = tid & 7;
    const float4* e4 = (const float4*)(et + x * N2 + part * 72);
    const float4* r4 = (const float4*)(r + part * 72);
    float acc = 0.f;
#pragma unroll
    for (int q = 0; q < 18; q++) {
      float4 a = e4[q]; float4 c = r4[q];
      acc = fmaf(a.x, c.x, fmaf(a.y, c.y, fmaf(a.z, c.z, fmaf(a.w, c.w, acc))));
    }
    partial[tid] = acc;
  }
  __syncthreads();
  if (tid < N) {
    float acc = 0.f;
    for (int q = 0; q < 8; q++) acc += partial[tid * 8 + q];
    beta[((b * N + tid) * T + i) * T + j] = tmv[0] + M + logf(fmaxf(acc, EPSV));
  }
}

// ---------------------------------------------------------------- outside cL
// parent (i,j): w[y,z]=sum_x et[x,y,z]*ea[x]; for each split s:
// cL[y] = log(sum_z w[y,z]*erb[z]) + tm + ma + mrb_s -> logaddexp into alpha[b,y,i,i+s]
__global__ void __launch_bounds__(256) outside_cL(
    const float* __restrict__ etT, const float* __restrict__ tmv,
    const float* __restrict__ beta, float* __restrict__ alpha, int l) {
  int i = blockIdx.x, b = blockIdx.y;
  int j = i + l - 1, S = l - 1, tid = threadIdx.x;
  __shared__ float ea[N];
  __shared__ __align__(16) float w[N2];
  __shared__ __align__(16) float eb[31 * N];
  __shared__ float mm[31];
  __shared__ float mash;
  const float* ab = alpha + b * N * T * T;
  const float* bbm = beta + b * N * T * T;

  if (tid < N) ea[tid] = ab[tid * T * T + i * T + j];
  __syncthreads();
  if (tid == 0) {
    float m = ea[0];
    for (int x = 1; x < N; x++) m = fmaxf(m, ea[x]);
    mash = m;
  }
  __syncthreads();
  float ma = mash;
  if (tid < N) ea[tid] = expf(ea[tid] - ma);
  __syncthreads();
  for (int p = tid; p < N2; p += 256) {
    const float4* e4 = (const float4*)(etT + p * N);
    float acc = 0.f;
#pragma unroll
    for (int x = 0; x < 6; x++) {
      float4 a = e4[x];
      acc = fmaf(a.x, ea[4 * x], fmaf(a.y, ea[4 * x + 1],
            fmaf(a.z, ea[4 * x + 2], fmaf(a.w, ea[4 * x + 3], acc))));
    }
    w[p] = acc;
  }
  for (int idx = tid; idx < S * N; idx += 256) {
    int s = idx / N, z = idx - (idx / N) * N;
    eb[idx] = bbm[z * T * T + (i + s + 1) * T + j];
  }
  __syncthreads();
  if (tid < S) {
    float m = eb[tid * N];
    for (int z = 1; z < N; z++) m = fmaxf(m, eb[tid * N + z]);
    mm[tid] = m;
  }
  __syncthreads();
  for (int idx = tid; idx < S * N; idx += 256) {
    int s = idx / N;
    eb[idx] = expf(eb[idx] - mm[s]);
  }
  __syncthreads();
  float tm = tmv[0];
  for (int idx = tid; idx < S * N; idx += 256) {
    int s = idx / N, y = idx - (idx / N) * N;
    const float4* w4 = (const float4*)(w + y * N);
    const float4* b4 = (const float4*)(eb + s * N);
    float acc = 0.f;
#pragma unroll
    for (int q = 0; q < 6; q++) {
      float4 a = w4[q]; float4 c = b4[q];
      acc = fmaf(a.x, c.x, fmaf(a.y, c.y, fmaf(a.z, c.z, fmaf(a.w, c.w, acc))));
    }
    float cl = logf(fmaxf(acc, EPSV)) + tm + ma + mm[s];
    float* tgt = alpha + ((b * N + y) * T + i) * T + (i + s);
    float old = *tgt;
    float mx = fmaxf(old, cl), mn = fminf(old, cl);
    *tgt = mx + log1pf(expf(mn - mx));
  }
}

// ---------------------------------------------------------------- outside cR
__global__ void __launch_bounds__(256) outside_cR(
    const float* __restrict__ etT, const float* __restrict__ tmv,
    const float* __restrict__ beta, float* __restrict__ alpha, int l) {
  int i = blockIdx.x, b = blockIdx.y;
  int j = i + l - 1, S = l - 1, tid = threadIdx.x;
  __shared__ float ea[N];
  __shared__ __align__(16) float w[N2];
  __shared__ __align__(16) float eb[31 * N];
  __shared__ float mm[31];
  __shared__ float mash;
  const float* ab = alpha + b * N * T * T;
  const float* bbm = beta + b * N * T * T;

  if (tid < N) ea[tid] = ab[tid * T * T + i * T + j];
  __syncthreads();
  if (tid == 0) {
    float m = ea[0];
    for (int x = 1; x < N; x++) m = fmaxf(m, ea[x]);
    mash = m;
  }
  __syncthreads();
  float ma = mash;
  if (tid < N) ea[tid] = expf(ea[tid] - ma);
  __syncthreads();
  for (int p = tid; p < N2; p += 256) {
    const float4* e4 = (const float4*)(etT + p * N);
    float acc = 0.f;
#pragma unroll
    for (int x = 0; x < 6; x++) {
      float4 a = e4[x];
      acc = fmaf(a.x, ea[4 * x], fmaf(a.y, ea[4 * x + 1],
            fmaf(a.z, ea[4 * x + 2], fmaf(a.w, ea[4 * x + 3], acc))));
    }
    w[p] = acc;
  }
  for (int idx = tid; idx < S * N; idx += 256) {
    int s = idx / N, y = idx - (idx / N) * N;
    eb[idx] = bbm[y * T * T + i * T + (i + s)];  // left-children beta
  }
  __syncthreads();
  if (tid < S) {
    float m = eb[tid * N];
    for (int y = 1; y < N; y++) m = fmaxf(m, eb[tid * N + y]);
    mm[tid] = m;
  }
  __syncthreads();
  for (int idx = tid; idx < S * N; idx += 256) {
    int s = idx / N;
    eb[idx] = expf(eb[idx] - mm[s]);
  }
  __syncthreads();
  float tm = tmv[0];
  for (int idx = tid; idx < S * N; idx += 256) {
    int s = idx / N, z = idx - (idx / N) * N;
    float acc = 0.f;
    for (int y = 0; y < N; y++) acc = fmaf(w[y * N + z], eb[s * N + y], acc);
    float cr = logf(fmaxf(acc, EPSV)) + tm + ma + mm[s];
    float* tgt = alpha + ((b * N + z) * T + (i + s + 1)) * T + j;
    float old = *tgt;
    float mx = fmaxf(old, cr), mn = fminf(old, cr);
    *tgt = mx + log1pf(expf(mn - mx));
  }
}

// ---------------------------------------------------------------- p_nt + loss
__global__ void pnt_kernel(const float* __restrict__ beta, const float* __restrict__ alpha,
                           float* __restrict__ pnt, float* __restrict__ lout) {
  int idx = blockIdx.x * 256 + threadIdx.x;
  if (idx < B * N * T) {
    int b = idx / (N * T);
    int t = idx & 31;
    int n = (idx >> 5) % N;
    float logZ = beta[(b * N) * T * T + (T - 1)];
    float bd = beta[(b * N + n) * T * T + t * T + t];
    float ad = alpha[(b * N + n) * T * T + t * T + t];
    pnt[idx] = expf(ad + bd - logZ);
  }
  if (idx == 0) {
    float ssum = 0.f;
    for (int b = 0; b < B; b++) ssum += beta[(b * N) * T * T + (T - 1)];
    lout[0] = -ssum / (float)B;
  }
}

// ---------------------------------------------------------------- mask logits
// out[b,t,v] = log(1e-6 + sum_n p_nt[b,n,t] * vocab[n,v])
__global__ void __launch_bounds__(256) mask_kernel(
    const float* __restrict__ pnt, const float* __restrict__ vocab,
    float* __restrict__ out) {
  int b = blockIdx.y;
  int v = blockIdx.x * 256 + threadIdx.x;  // V = 125*256 exactly
  __shared__ float p[N * T];
  for (int idx = threadIdx.x; idx < N * T; idx += 256) p[idx] = pnt[b * N * T + idx];
  __syncthreads();
  float vr[N];
#pragma unroll
  for (int n = 0; n < N; n++) vr[n] = vocab[n * V + v];
  float* ob = out + (size_t)b * T * V + v;
  for (int t = 0; t < T; t++) {
    float acc = 1e-6f;
#pragma unroll
    for (int n = 0; n < N; n++) acc = fmaf(p[n * T + t], vr[n], acc);
    ob[(size_t)t * V] = logf(acc);
  }
}

// ---------------------------------------------------------------- launch
extern "C" void kernel_launch(void* const* d_in, const int* in_sizes, int n_in,
                              void* d_out, int out_size, void* d_ws, size_t ws_size,
                              hipStream_t stream) {
  const float* g_seq   = (const float*)d_in[0];
  const float* Theta   = (const float*)d_in[1];
  const float* vocab   = (const float*)d_in[2];
  const float* ln_g    = (const float*)d_in[3];
  const float* ln_b    = (const float*)d_in[4];
  const float* W1      = (const float*)d_in[5];
  const float* b1      = (const float*)d_in[6];
  const float* W2      = (const float*)d_in[7];
  const float* b2      = (const float*)d_in[8];
  float* out = (float*)d_out;

  float* ws = (float*)d_ws;
  float* Phi  = ws;                 // 12288
  float* et   = Phi + 12288;        // 13824
  float* etT  = et + 13824;         // 13824
  float* tmv  = etT + 13824;        // 1  (round region up to 40960)
  float* beta  = ws + 40960;        // 393216
  float* alpha = beta + 393216;     // 393216
  float* pnt   = alpha + 393216;    // 12288

  frontend_kernel<<<dim3(B * T), dim3(128), 0, stream>>>(g_seq, ln_g, ln_b, W1, b1, W2, b2, Phi);
  theta_prep<<<dim3(1), dim3(576), 0, stream>>>(Theta, et, etT, tmv);
  init_kernel<<<dim3(1536), dim3(256), 0, stream>>>(Phi, beta, alpha);

  for (int l = 2; l <= T; l++)
    inside_level<<<dim3(T - l + 1, B), dim3(256), 0, stream>>>(et, tmv, beta, l);

  for (int l = T; l >= 2; l--) {
    outside_cL<<<dim3(T - l + 1, B), dim3(256), 0, stream>>>(etT, tmv, beta, alpha, l);
    outside_cR<<<dim3(T - l + 1, B), dim3(256), 0, stream>>>(etT, tmv, beta, alpha, l);
  }

  pnt_kernel<<<dim3(48), dim3(256), 0, stream>>>(beta, alpha, pnt, out + (size_t)B * T * V);
  mask_kernel<<<dim3(125, B), dim3(256), 0, stream>>>(pnt, vocab, out);
}